// Round 1
// baseline (1961.196 us; speedup 1.0000x reference)
//
#include <hip/hip_runtime.h>
#include <hip/hip_bf16.h>
#include <math.h>

typedef __attribute__((ext_vector_type(8))) short short8;
typedef __attribute__((ext_vector_type(4))) float f32x4;

#define MFMA16(a, b, c) __builtin_amdgcn_mfma_f32_16x16x32_bf16((a), (b), (c), 0, 0, 0)

#define BB 256
#define TT 64
#define VOCAB 10000
#define WORD 512
#define RNN 512
#define NC 2560          /* 2048 gates + 512 sentinel-gate pre */
#define NV 10001
#define NVP 10016
#define NTILES 626       /* NVP/16 */

__device__ __forceinline__ float sigf(float x) { return 1.f / (1.f + __expf(-x)); }
__device__ __forceinline__ float bf2f(short s) {
    union { unsigned int u; float f; } v;
    v.u = ((unsigned int)(unsigned short)s) << 16;
    return v.f;
}
__device__ __forceinline__ short f2bfs(float x) {
    __hip_bfloat16 h = __float2bfloat16(x);
    return *reinterpret_cast<short*>(&h);
}

// async global->LDS, 16B per lane. lds dest = wave-uniform base + lane*16 (HW rule).
__device__ __forceinline__ void gload_lds16(const void* g, void* l) {
    __builtin_amdgcn_global_load_lds((const __attribute__((address_space(1))) void*)g,
                                     (__attribute__((address_space(3))) void*)l, 16, 0, 0);
}

// stage one 16KB fragment-order tile: 4 waves x 4KB each
__device__ __forceinline__ void stage_tile(const short8* gsrc, void* lbuf, int w, int lane) {
    const char* g = (const char*)gsrc + w * 4096 + lane * 16;
    char* l = (char*)lbuf + w * 4096;
#pragma unroll
    for (int i = 0; i < 4; i++) gload_lds16(g + i * 1024, l + i * 1024);
}

// ---------------- prep kernels ----------------

// dst[n][k] = (float->bf16) src[k][n]; zero-fill for n in [N, dstN)
__global__ void transpose_cvt(const float* __restrict__ src, int K, int N, int ld,
                              __hip_bfloat16* __restrict__ dst, int dst_ld, int dstN) {
    __shared__ float tile[32][33];
    int k0 = blockIdx.y * 32, n0 = blockIdx.x * 32;
    int tx = threadIdx.x, ty = threadIdx.y;   // 32 x 8
#pragma unroll
    for (int i = 0; i < 32; i += 8) {
        int k = k0 + ty + i, n = n0 + tx;
        tile[ty + i][tx] = (k < K && n < N) ? src[(size_t)k * ld + n] : 0.f;
    }
    __syncthreads();
#pragma unroll
    for (int i = 0; i < 32; i += 8) {
        int n = n0 + ty + i, k = k0 + tx;
        if (n < dstN && k < K) dst[(size_t)n * dst_ld + k] = __float2bfloat16(tile[tx][ty + i]);
    }
}

// [ntiles*16][512] ([N][K]) -> fragment order: dst[ct][kt][lane] = src[(ct*16+(l&15))][kt*32+(l>>4)*8 ..+7]
__global__ void swizzle_frag(const short8* __restrict__ src, short8* __restrict__ dst, int ntiles) {
    int t = blockIdx.x * 256 + threadIdx.x;
    if (t >= ntiles * 1024) return;
    int ct = t >> 10, r = t & 1023, kt = r >> 6, l = r & 63;
    int li = l & 15, q = l >> 4;
    dst[t] = src[(size_t)(ct * 16 + li) * 64 + kt * 4 + q];
}

__global__ void zero_state(float* c, __hip_bfloat16* h) {
    int idx = blockIdx.x * 256 + threadIdx.x;   // 131072
    c[idx] = 0.f;
    h[idx] = __float2bfloat16(0.f);
}

__global__ void cvt_vis(const float* __restrict__ v, __hip_bfloat16* __restrict__ d) {
    int idx = blockIdx.x * 256 + threadIdx.x;   // 262144
    d[idx] = __float2bfloat16(v[idx]);
}

// visC[256][2560] = vis_bf16 @ visW + bias (b_lstm for n<2048 else vis2g_b)
__global__ __launch_bounds__(256) void gemm_vis(const __hip_bfloat16* __restrict__ A,
                                                const __hip_bfloat16* __restrict__ Bt,
                                                const float* __restrict__ b_lstm,
                                                const float* __restrict__ vis2g_b,
                                                float* __restrict__ C) {
    int wid = blockIdx.x * 4 + (threadIdx.x >> 6);   // 2560 waves: 16 x 160 tiles
    int mt = wid / 160, nt = wid % 160;
    int lane = threadIdx.x & 63, li = lane & 15, q = lane >> 4;
    const short8* Ap = (const short8*)A + (mt * 16 + li) * 128 + q;   // ld 1024 -> 128 chunks
    const short8* Bp = (const short8*)Bt + (nt * 16 + li) * 128 + q;
    f32x4 acc = {0.f, 0.f, 0.f, 0.f};
#pragma unroll
    for (int kk = 0; kk < 128; kk += 4) acc = MFMA16(Ap[kk], Bp[kk], acc);
    int col = nt * 16 + li;
    float bias = (col < 2048) ? b_lstm[col] : vis2g_b[col - 2048];
#pragma unroll
    for (int r = 0; r < 4; r++) {
        int row = mt * 16 + q * 4 + r;
        C[row * NC + col] = acc[r] + bias;
    }
}

// preF in C-FRAGMENT order: preF[(rowtile*160 + ct)*256 + lane*4 + r]  (bf16)
//   rowtile = (t*256+b)>>4, ct = gate*32 + jt, lane = q*16+li holds col=li rows q*4+r.
// pre_gemm's accumulator IS this fragment, so the store is a coalesced 8B/lane write.
__global__ __launch_bounds__(256) void pre_gemm(const int* __restrict__ seqz,
                                                const float* __restrict__ emb,
                                                const short8* __restrict__ Bsw,   // 160 tiles, frag order
                                                const float* __restrict__ visC,
                                                __hip_bfloat16* __restrict__ preF) {
    __shared__ short8 lds[2][1024];
    int w = threadIdx.x >> 6, lane = threadIdx.x & 63, li = lane & 15, q = lane >> 4;
    int r0 = blockIdx.x * 128 + w * 32;

    short8 a0[16], a1[16];
    {
        int row = r0 + li;
        int t = row >> 8, b = row & 255;
        int wid_ = (t == 0) ? (VOCAB + 1) : seqz[b * TT + (t - 1)];
        const float* er = emb + (size_t)wid_ * WORD + q * 8;
#pragma unroll
        for (int kt = 0; kt < 16; kt++) {
            float4 f0 = ((const float4*)(er + kt * 32))[0];
            float4 f1 = ((const float4*)(er + kt * 32))[1];
            short8 v; v[0]=f2bfs(f0.x); v[1]=f2bfs(f0.y); v[2]=f2bfs(f0.z); v[3]=f2bfs(f0.w);
            v[4]=f2bfs(f1.x); v[5]=f2bfs(f1.y); v[6]=f2bfs(f1.z); v[7]=f2bfs(f1.w);
            a0[kt] = v;
        }
        row = r0 + 16 + li; t = row >> 8; b = row & 255;
        wid_ = (t == 0) ? (VOCAB + 1) : seqz[b * TT + (t - 1)];
        er = emb + (size_t)wid_ * WORD + q * 8;
#pragma unroll
        for (int kt = 0; kt < 16; kt++) {
            float4 f0 = ((const float4*)(er + kt * 32))[0];
            float4 f1 = ((const float4*)(er + kt * 32))[1];
            short8 v; v[0]=f2bfs(f0.x); v[1]=f2bfs(f0.y); v[2]=f2bfs(f0.z); v[3]=f2bfs(f0.w);
            v[4]=f2bfs(f1.x); v[5]=f2bfs(f1.y); v[6]=f2bfs(f1.z); v[7]=f2bfs(f1.w);
            a1[kt] = v;
        }
    }

    int t0 = blockIdx.y * 20, t1 = t0 + 20;   // 8 chunks x 20 = 160
    stage_tile(Bsw + (size_t)t0 * 1024, lds[0], w, lane);
    int ib = 0;
    for (int ct = t0; ct < t1; ++ct, ib ^= 1) {
        __syncthreads();
        if (ct + 1 < t1) stage_tile(Bsw + (size_t)(ct + 1) * 1024, lds[ib ^ 1], w, lane);
        const short8* B = lds[ib];
        f32x4 c0 = {0.f,0.f,0.f,0.f}, c1 = {0.f,0.f,0.f,0.f};
#pragma unroll
        for (int kt = 0; kt < 16; kt++) {
            short8 bv = B[kt * 64 + lane];
            c0 = MFMA16(a0[kt], bv, c0);
            c1 = MFMA16(a1[kt], bv, c1);
        }
        int col = ct * 16 + li;
        size_t tb0 = ((size_t)(r0 >> 4) * 160 + ct) * 256 + lane * 4;
        size_t tb1 = tb0 + (size_t)160 * 256;
#pragma unroll
        for (int r = 0; r < 4; r++) {
            int row0 = r0 + q * 4 + r, row1 = row0 + 16;
            preF[tb0 + r] = __float2bfloat16(c0[r] + visC[(row0 & 255) * NC + col]);
            preF[tb1 + r] = __float2bfloat16(c1[r] + visC[(row1 & 255) * NC + col]);
        }
    }
}

// ---------------- persistent recurrence kernel ----------------
// 512 blocks x 1 wave (cooperative). Wave (mt,jt): rows mt*16..+15, cols jt*16..+15 of each
// of the 5 gate blocks. B: gates 0..3 in 64KB LDS (staged once), gate 4 (sentinel) in VGPRs.
// c stays in registers for all 64 steps. h exchanged via global between the 32 waves of an
// mt-group, synchronized by a per-mt sense-reversing barrier (agent-scope acq/rel: release
// emits vmcnt(0)+buffer_wbl2, acquire emits buffer_inv -> cross-XCD h visibility; vmcnt(0)
// also closes the h double-buffer WAR window).
__global__ __launch_bounds__(64, 1) void lstm_persist(const short8* __restrict__ WHsw,
                                                      const __hip_bfloat16* __restrict__ preF,
                                                      __hip_bfloat16* __restrict__ h0,
                                                      __hip_bfloat16* __restrict__ h1,
                                                      __hip_bfloat16* __restrict__ S,
                                                      int* __restrict__ bars) {
    __shared__ short8 ldsB[4096];   // 64 KB: 4 gate tiles x 16KB, fragment order
    int wid = blockIdx.x;           // 0..511
    int mt = wid >> 5, jt = wid & 31;
    int lane = threadIdx.x;
    int li = lane & 15, q = lane >> 4;

    // stage gate tiles 0..3 -> LDS (linear copy of frag-order tiles)
#pragma unroll
    for (int g = 0; g < 4; ++g) {
        const char* src = (const char*)(WHsw + (size_t)(g * 32 + jt) * 1024) + lane * 16;
        char* dst = (char*)ldsB + g * 16384;
#pragma unroll
        for (int i = 0; i < 16; ++i) gload_lds16(src + i * 1024, dst + i * 1024);
    }
    // sentinel gate tile -> registers
    short8 b4[16];
    const short8* B4 = WHsw + (size_t)(128 + jt) * 1024 + lane;
#pragma unroll
    for (int kt = 0; kt < 16; ++kt) b4[kt] = B4[kt * 64];
    __syncthreads();   // drains vmcnt -> gload_lds data usable

    int* cnt = bars + mt * 64;        // 256B-strided groups; cnt/gen 128B apart
    int* gen = bars + mt * 64 + 32;

    f32x4 cacc = {0.f, 0.f, 0.f, 0.f};
    int jcol = jt * 16 + li;

    for (int t = 0; t < TT; ++t) {
        const __hip_bfloat16* hc = (t & 1) ? h1 : h0;
        __hip_bfloat16*       hn = (t & 1) ? h0 : h1;

        // pre prefetch: 5 gates x 8B (4 bf16), coalesced; hidden under MFMA phase
        unsigned long long pp[5];
        size_t prow = (size_t)(t * 16 + mt) * 160;
#pragma unroll
        for (int g = 0; g < 5; ++g)
            pp[g] = *(const unsigned long long*)((const char*)preF +
                     ((prow + g * 32 + jt) * 256 + lane * 4) * 2);

        // A fragments from h (16 x 16B)
        const short8* Ap = (const short8*)hc + (size_t)(mt * 16 + li) * 64 + q;
        short8 av[16];
#pragma unroll
        for (int kt = 0; kt < 16; ++kt) av[kt] = Ap[kt * 4];

        f32x4 g0 = {0.f,0.f,0.f,0.f}, g1 = g0, g2 = g0, g3 = g0, g4 = g0;
#pragma unroll
        for (int kt = 0; kt < 16; ++kt) {
            g0 = MFMA16(av[kt], ldsB[          kt * 64 + lane], g0);
            g1 = MFMA16(av[kt], ldsB[1024 +    kt * 64 + lane], g1);
            g2 = MFMA16(av[kt], ldsB[2048 +    kt * 64 + lane], g2);
            g3 = MFMA16(av[kt], ldsB[3072 +    kt * 64 + lane], g3);
            g4 = MFMA16(av[kt], b4[kt], g4);
        }

        __hip_bfloat16* Sp = S + (size_t)t * 131072;
#pragma unroll
        for (int r = 0; r < 4; ++r) {
            float ig = sigf(g0[r] + bf2f((short)(pp[0] >> (r * 16))));
            float fg = sigf(g1[r] + bf2f((short)(pp[1] >> (r * 16))));
            float gg = tanhf(g2[r] + bf2f((short)(pp[2] >> (r * 16))));
            float og = sigf(g3[r] + bf2f((short)(pp[3] >> (r * 16))));
            float gp = sigf(g4[r] + bf2f((short)(pp[4] >> (r * 16))));
            float cn = fg * cacc[r] + ig * gg;
            float tc = tanhf(cn);
            cacc[r] = cn;
            int row = mt * 16 + q * 4 + r;
            hn[row * 512 + jcol] = __float2bfloat16(og * tc);
            Sp[row * 512 + jcol] = __float2bfloat16(gp * tc);
        }

        // per-mt-group barrier (32 arrivals), sense-reversing via generation counter
        asm volatile("" ::: "memory");
        if (lane == 0) {
            int g = __hip_atomic_load(gen, __ATOMIC_RELAXED, __HIP_MEMORY_SCOPE_AGENT);
            int a = __hip_atomic_fetch_add(cnt, 1, __ATOMIC_ACQ_REL, __HIP_MEMORY_SCOPE_AGENT);
            if (a == 31) {
                __hip_atomic_store(cnt, 0, __ATOMIC_RELAXED, __HIP_MEMORY_SCOPE_AGENT);
                __hip_atomic_store(gen, g + 1, __ATOMIC_RELEASE, __HIP_MEMORY_SCOPE_AGENT);
            } else {
                while (__hip_atomic_load(gen, __ATOMIC_RELAXED, __HIP_MEMORY_SCOPE_AGENT) <= g)
                    __builtin_amdgcn_s_sleep(2);
                (void)__hip_atomic_load(gen, __ATOMIC_ACQUIRE, __HIP_MEMORY_SCOPE_AGENT);
            }
        }
        asm volatile("" ::: "memory");
    }
}

// ---------------- fused output GEMM + sum-exp ----------------

__global__ __launch_bounds__(256) void lse_gemm(const short8* __restrict__ S8,
                                                const short8* __restrict__ Bsw,
                                                const float* __restrict__ ob,
                                                float* __restrict__ sumexp) {
    __shared__ short8 lds[2][1024];
    int w = threadIdx.x >> 6, lane = threadIdx.x & 63, li = lane & 15, q = lane >> 4;
    int r0 = blockIdx.x * 128 + w * 32;
    short8 a0[16], a1[16];
    const short8* Sp0 = S8 + (size_t)(r0 + li) * 64 + q;
    const short8* Sp1 = S8 + (size_t)(r0 + 16 + li) * 64 + q;
#pragma unroll
    for (int kt = 0; kt < 16; kt++) { a0[kt] = Sp0[kt * 4]; a1[kt] = Sp1[kt * 4]; }

    float s0[4] = {0.f,0.f,0.f,0.f}, s1[4] = {0.f,0.f,0.f,0.f};
    int t0 = blockIdx.y * 40;
    int t1 = t0 + 40 < NTILES ? t0 + 40 : NTILES;   // last chunk = 26

    stage_tile(Bsw + (size_t)t0 * 1024, lds[0], w, lane);
    int ib = 0;
    for (int ct = t0; ct < t1; ++ct, ib ^= 1) {
        __syncthreads();
        if (ct + 1 < t1) stage_tile(Bsw + (size_t)(ct + 1) * 1024, lds[ib ^ 1], w, lane);
        const short8* B = lds[ib];
        f32x4 c0 = {0.f,0.f,0.f,0.f}, c1 = {0.f,0.f,0.f,0.f};
#pragma unroll
        for (int kt = 0; kt < 16; kt++) {
            short8 bv = B[kt * 64 + lane];
            c0 = MFMA16(a0[kt], bv, c0);
            c1 = MFMA16(a1[kt], bv, c1);
        }
        int col = ct * 16 + li;
        if (col < NV) {
            float obv = ob[col];
#pragma unroll
            for (int r = 0; r < 4; r++) {
                s0[r] += __expf(c0[r] + obv);
                s1[r] += __expf(c1[r] + obv);
            }
        }
    }
#pragma unroll
    for (int off = 1; off < 16; off <<= 1) {
#pragma unroll
        for (int r = 0; r < 4; r++) { s0[r] += __shfl_xor(s0[r], off); s1[r] += __shfl_xor(s1[r], off); }
    }
    if (li == 0) {
#pragma unroll
        for (int r = 0; r < 4; r++) {
            atomicAdd(&sumexp[r0 + q * 4 + r], s0[r]);
            atomicAdd(&sumexp[r0 + 16 + q * 4 + r], s1[r]);
        }
    }
}

// out[row] = mask * (dot(S[row], out_W[:,tgt]) + ob[tgt] - log(sumexp[row]))
__global__ __launch_bounds__(256) void finalize_k(const __hip_bfloat16* __restrict__ S,
                                                  const __hip_bfloat16* __restrict__ Wt,
                                                  const float* __restrict__ ob,
                                                  const int* __restrict__ seqz,
                                                  const float* __restrict__ sumexp,
                                                  float* __restrict__ out) {
    int w = threadIdx.x >> 6, lane = threadIdx.x & 63;
    int row = blockIdx.x * 4 + w;        // 16384 rows, row = t*256 + b
    int t = row >> 8, b = row & 255;
    int tgt = seqz[b * TT + t];
    short8 sv = ((const short8*)(S + (size_t)row * 512))[lane];
    short8 wv = ((const short8*)(Wt + (size_t)tgt * 512))[lane];
    float d = 0.f;
#pragma unroll
    for (int i = 0; i < 8; i++) d += bf2f(sv[i]) * bf2f(wv[i]);
#pragma unroll
    for (int off = 1; off < 64; off <<= 1) d += __shfl_xor(d, off);
    if (lane == 0) {
        bool mk = (t == 0) || (seqz[b * TT + t - 1] != 0);
        out[row] = mk ? (d + ob[tgt] - logf(sumexp[row])) : 0.f;
    }
}

// ---------------- host ----------------

extern "C" void kernel_launch(void* const* d_in, const int* in_sizes, int n_in,
                              void* d_out, int out_size, void* d_ws, size_t ws_size,
                              hipStream_t stream) {
    const float* vis     = (const float*)d_in[0];
    const int*   seqz    = (const int*)d_in[1];
    const float* emb     = (const float*)d_in[2];
    const float* W_ih    = (const float*)d_in[3];
    const float* W_hh    = (const float*)d_in[4];
    const float* b_lstm  = (const float*)d_in[5];
    const float* vis2g_W = (const float*)d_in[6];
    const float* vis2g_b = (const float*)d_in[7];
    const float* w2g_W   = (const float*)d_in[8];
    const float* h2g_W   = (const float*)d_in[9];
    const float* out_W   = (const float*)d_in[10];
    const float* out_b   = (const float*)d_in[11];
    float* out = (float*)d_out;

    char* p = (char*)d_ws;
    auto carve = [&](size_t bytes) {
        void* r = (void*)p;
        p += (bytes + 255) & ~(size_t)255;
        return r;
    };
    __hip_bfloat16* WcatW = (__hip_bfloat16*)carve((size_t)NC * 512 * 2);       // [2560][512]
    __hip_bfloat16* WcatH = (__hip_bfloat16*)carve((size_t)NC * 512 * 2);       // [2560][512]
    __hip_bfloat16* visWt = (__hip_bfloat16*)carve((size_t)NC * 1024 * 2);      // [2560][1024]
    __hip_bfloat16* outWt = (__hip_bfloat16*)carve((size_t)NVP * 512 * 2);      // [10016][512]
    short8*         outSw = (short8*)carve((size_t)NTILES * 16384);             // frag order
    short8*         preBsw= (short8*)carve((size_t)160 * 16384);                // frag order
    short8*         WHsw  = (short8*)carve((size_t)160 * 16384);                // frag order
    __hip_bfloat16* visB  = (__hip_bfloat16*)carve((size_t)256 * 1024 * 2);
    float*          visC  = (float*)carve((size_t)256 * NC * 4);
    __hip_bfloat16* preF  = (__hip_bfloat16*)carve((size_t)TT * 256 * NC * 2);  // 84 MB, frag order
    float*          cbuf  = (float*)carve((size_t)256 * 512 * 4);               // unused by persist (c in regs)
    __hip_bfloat16* hb0   = (__hip_bfloat16*)carve((size_t)256 * 512 * 2);
    __hip_bfloat16* hb1   = (__hip_bfloat16*)carve((size_t)256 * 512 * 2);
    __hip_bfloat16* S     = (__hip_bfloat16*)carve((size_t)TT * 256 * 512 * 2);
    float*          sume  = (float*)carve((size_t)TT * 256 * 4);
    int*            bars  = (int*)carve((size_t)16 * 64 * 4);                   // 16 groups: cnt/gen

    dim3 tb(32, 8);
    // WcatW: word -> [gates | w2g];  WcatH: h -> [gates | h2g]   (both [2560][512] = [N][K])
    transpose_cvt<<<dim3(64, 16), tb, 0, stream>>>(W_ih + 1024 * 2048, 512, 2048, 2048, WcatW, 512, 2048);
    transpose_cvt<<<dim3(16, 16), tb, 0, stream>>>(w2g_W, 512, 512, 512, WcatW + 2048 * 512, 512, 512);
    transpose_cvt<<<dim3(64, 16), tb, 0, stream>>>(W_hh, 512, 2048, 2048, WcatH, 512, 2048);
    transpose_cvt<<<dim3(16, 16), tb, 0, stream>>>(h2g_W, 512, 512, 512, WcatH + 2048 * 512, 512, 512);
    // visWt: vis -> [gates | vis2g]  [2560][1024]
    transpose_cvt<<<dim3(64, 32), tb, 0, stream>>>(W_ih, 1024, 2048, 2048, visWt, 1024, 2048);
    transpose_cvt<<<dim3(16, 32), tb, 0, stream>>>(vis2g_W, 1024, 512, 512, visWt + 2048 * 1024, 1024, 512);
    // out_W transposed, zero-padded to 10016 rows
    transpose_cvt<<<dim3(313, 16), tb, 0, stream>>>(out_W, 512, NV, NV, outWt, 512, NVP);
    // fragment-order swizzles
    swizzle_frag<<<2504, 256, 0, stream>>>((const short8*)outWt, outSw, NTILES);
    swizzle_frag<<<640, 256, 0, stream>>>((const short8*)WcatW, preBsw, 160);
    swizzle_frag<<<640, 256, 0, stream>>>((const short8*)WcatH, WHsw, 160);

    zero_state<<<512, 256, 0, stream>>>(cbuf, hb0);
    cvt_vis<<<1024, 256, 0, stream>>>(vis, visB);
    gemm_vis<<<640, 256, 0, stream>>>(visB, visWt, b_lstm, vis2g_b, visC);
    pre_gemm<<<dim3(128, 8), 256, 0, stream>>>(seqz, emb, preBsw, visC, preF);

    hipMemsetAsync(sume, 0, (size_t)TT * 256 * 4, stream);
    hipMemsetAsync(bars, 0, (size_t)16 * 64 * 4, stream);

    // all 64 recurrence steps in one cooperative persistent kernel
    {
        const short8* WHsw_c = (const short8*)WHsw;
        const __hip_bfloat16* preF_c = (const __hip_bfloat16*)preF;
        __hip_bfloat16* h0a = hb0;
        __hip_bfloat16* h1a = hb1;
        __hip_bfloat16* Sa = S;
        int* barsa = bars;
        void* kargs[6] = { &WHsw_c, &preF_c, &h0a, &h1a, &Sa, &barsa };
        hipLaunchCooperativeKernel((void*)lstm_persist, dim3(512), dim3(64), kargs, 0, stream);
    }

    lse_gemm<<<dim3(128, 16), 256, 0, stream>>>((const short8*)S, outSw, out_b, sume);
    finalize_k<<<4096, 256, 0, stream>>>(S, outWt, out_b, seqz, sume, out);
}

// Round 3
// 730.057 us; speedup vs baseline: 2.6864x; 2.6864x over previous
//
#include <hip/hip_runtime.h>
#include <hip/hip_bf16.h>
#include <math.h>

typedef __attribute__((ext_vector_type(8))) short short8;
typedef __attribute__((ext_vector_type(4))) float f32x4;

#define MFMA16(a, b, c) __builtin_amdgcn_mfma_f32_16x16x32_bf16((a), (b), (c), 0, 0, 0)

#define BB 256
#define TT 64
#define VOCAB 10000
#define WORD 512
#define RNN 512
#define NC 2560          /* 2048 gates + 512 sentinel-gate pre */
#define NV 10001
#define NVP 10016
#define NTILES 626       /* NVP/16 */

typedef unsigned long long ull;
union U16 { ull u[2]; short8 s8; };

__device__ __forceinline__ float sigf(float x) { return 1.f / (1.f + __expf(-x)); }
__device__ __forceinline__ float bf2f(short s) {
    union { unsigned int u; float f; } v;
    v.u = ((unsigned int)(unsigned short)s) << 16;
    return v.f;
}
__device__ __forceinline__ short f2bfs(float x) {
    __hip_bfloat16 h = __float2bfloat16(x);
    return *reinterpret_cast<short*>(&h);
}

// async global->LDS, 16B per lane. lds dest = wave-uniform base + lane*16 (HW rule).
__device__ __forceinline__ void gload_lds16(const void* g, void* l) {
    __builtin_amdgcn_global_load_lds((const __attribute__((address_space(1))) void*)g,
                                     (__attribute__((address_space(3))) void*)l, 16, 0, 0);
}

// stage one 16KB fragment-order tile: 4 waves x 4KB each
__device__ __forceinline__ void stage_tile(const short8* gsrc, void* lbuf, int w, int lane) {
    const char* g = (const char*)gsrc + w * 4096 + lane * 16;
    char* l = (char*)lbuf + w * 4096;
#pragma unroll
    for (int i = 0; i < 4; i++) gload_lds16(g + i * 1024, l + i * 1024);
}

// ---------------- prep kernels ----------------

// dst[n][k] = (float->bf16) src[k][n]; zero-fill for n in [N, dstN)
__global__ void transpose_cvt(const float* __restrict__ src, int K, int N, int ld,
                              __hip_bfloat16* __restrict__ dst, int dst_ld, int dstN) {
    __shared__ float tile[32][33];
    int k0 = blockIdx.y * 32, n0 = blockIdx.x * 32;
    int tx = threadIdx.x, ty = threadIdx.y;   // 32 x 8
#pragma unroll
    for (int i = 0; i < 32; i += 8) {
        int k = k0 + ty + i, n = n0 + tx;
        tile[ty + i][tx] = (k < K && n < N) ? src[(size_t)k * ld + n] : 0.f;
    }
    __syncthreads();
#pragma unroll
    for (int i = 0; i < 32; i += 8) {
        int n = n0 + ty + i, k = k0 + tx;
        if (n < dstN && k < K) dst[(size_t)n * dst_ld + k] = __float2bfloat16(tile[tx][ty + i]);
    }
}

// [ntiles*16][512] ([N][K]) -> fragment order: dst[ct][kt][lane] = src[(ct*16+(l&15))][kt*32+(l>>4)*8 ..+7]
__global__ void swizzle_frag(const short8* __restrict__ src, short8* __restrict__ dst, int ntiles) {
    int t = blockIdx.x * 256 + threadIdx.x;
    if (t >= ntiles * 1024) return;
    int ct = t >> 10, r = t & 1023, kt = r >> 6, l = r & 63;
    int li = l & 15, q = l >> 4;
    dst[t] = src[(size_t)(ct * 16 + li) * 64 + kt * 4 + q];
}

__global__ void zero_state(float* c, __hip_bfloat16* h) {
    int idx = blockIdx.x * 256 + threadIdx.x;   // 131072
    c[idx] = 0.f;
    h[idx] = __float2bfloat16(0.f);
}

__global__ void cvt_vis(const float* __restrict__ v, __hip_bfloat16* __restrict__ d) {
    int idx = blockIdx.x * 256 + threadIdx.x;   // 262144
    d[idx] = __float2bfloat16(v[idx]);
}

// visC[256][2560] = vis_bf16 @ visW + bias (b_lstm for n<2048 else vis2g_b)
__global__ __launch_bounds__(256) void gemm_vis(const __hip_bfloat16* __restrict__ A,
                                                const __hip_bfloat16* __restrict__ Bt,
                                                const float* __restrict__ b_lstm,
                                                const float* __restrict__ vis2g_b,
                                                float* __restrict__ C) {
    int wid = blockIdx.x * 4 + (threadIdx.x >> 6);   // 2560 waves: 16 x 160 tiles
    int mt = wid / 160, nt = wid % 160;
    int lane = threadIdx.x & 63, li = lane & 15, q = lane >> 4;
    const short8* Ap = (const short8*)A + (mt * 16 + li) * 128 + q;   // ld 1024 -> 128 chunks
    const short8* Bp = (const short8*)Bt + (nt * 16 + li) * 128 + q;
    f32x4 acc = {0.f, 0.f, 0.f, 0.f};
#pragma unroll
    for (int kk = 0; kk < 128; kk += 4) acc = MFMA16(Ap[kk], Bp[kk], acc);
    int col = nt * 16 + li;
    float bias = (col < 2048) ? b_lstm[col] : vis2g_b[col - 2048];
#pragma unroll
    for (int r = 0; r < 4; r++) {
        int row = mt * 16 + q * 4 + r;
        C[row * NC + col] = acc[r] + bias;
    }
}

// preF in TRANSPOSED-fragment order: preF[((rowtile*160 + ct)*256 + lane*4) + r]
//   = pre[row = rowtile*16 + (lane&15)][col = ct*16 + (lane>>4)*4 + r]
// i.e. each lane holds 4 consecutive COLUMNS of one row -> 8B contiguous store,
// and exactly the layout the persistent step consumes.
__global__ __launch_bounds__(256) void pre_gemm(const int* __restrict__ seqz,
                                                const float* __restrict__ emb,
                                                const short8* __restrict__ Bsw,   // 160 tiles, frag order
                                                const float* __restrict__ visC,
                                                __hip_bfloat16* __restrict__ preF) {
    __shared__ short8 lds[2][1024];
    int w = threadIdx.x >> 6, lane = threadIdx.x & 63, li = lane & 15, q = lane >> 4;
    int r0 = blockIdx.x * 128 + w * 32;

    short8 a0[16], a1[16];
    {
        int row = r0 + li;
        int t = row >> 8, b = row & 255;
        int wid_ = (t == 0) ? (VOCAB + 1) : seqz[b * TT + (t - 1)];
        const float* er = emb + (size_t)wid_ * WORD + q * 8;
#pragma unroll
        for (int kt = 0; kt < 16; kt++) {
            float4 f0 = ((const float4*)(er + kt * 32))[0];
            float4 f1 = ((const float4*)(er + kt * 32))[1];
            short8 v; v[0]=f2bfs(f0.x); v[1]=f2bfs(f0.y); v[2]=f2bfs(f0.z); v[3]=f2bfs(f0.w);
            v[4]=f2bfs(f1.x); v[5]=f2bfs(f1.y); v[6]=f2bfs(f1.z); v[7]=f2bfs(f1.w);
            a0[kt] = v;
        }
        row = r0 + 16 + li; t = row >> 8; b = row & 255;
        wid_ = (t == 0) ? (VOCAB + 1) : seqz[b * TT + (t - 1)];
        er = emb + (size_t)wid_ * WORD + q * 8;
#pragma unroll
        for (int kt = 0; kt < 16; kt++) {
            float4 f0 = ((const float4*)(er + kt * 32))[0];
            float4 f1 = ((const float4*)(er + kt * 32))[1];
            short8 v; v[0]=f2bfs(f0.x); v[1]=f2bfs(f0.y); v[2]=f2bfs(f0.z); v[3]=f2bfs(f0.w);
            v[4]=f2bfs(f1.x); v[5]=f2bfs(f1.y); v[6]=f2bfs(f1.z); v[7]=f2bfs(f1.w);
            a1[kt] = v;
        }
    }

    int t0 = blockIdx.y * 20, t1 = t0 + 20;   // 8 chunks x 20 = 160
    stage_tile(Bsw + (size_t)t0 * 1024, lds[0], w, lane);
    int ib = 0;
    for (int ct = t0; ct < t1; ++ct, ib ^= 1) {
        __syncthreads();
        if (ct + 1 < t1) stage_tile(Bsw + (size_t)(ct + 1) * 1024, lds[ib ^ 1], w, lane);
        const short8* B = lds[ib];
        f32x4 c0 = {0.f,0.f,0.f,0.f}, c1 = {0.f,0.f,0.f,0.f};
#pragma unroll
        for (int kt = 0; kt < 16; kt++) {
            short8 bv = B[kt * 64 + lane];
            // TRANSPOSED: A = W-frag, B = emb-frag -> lane holds batch row li, gate cols ct*16+q*4..+3
            c0 = MFMA16(bv, a0[kt], c0);
            c1 = MFMA16(bv, a1[kt], c1);
        }
        int col0 = ct * 16 + q * 4;
        size_t tb0 = ((size_t)(r0 >> 4) * 160 + ct) * 256 + lane * 4;
        size_t tb1 = tb0 + (size_t)160 * 256;
        float4 v0 = *(const float4*)(visC + ((r0 + li) & 255) * NC + col0);
        float4 v1 = *(const float4*)(visC + ((r0 + 16 + li) & 255) * NC + col0);
        preF[tb0 + 0] = __float2bfloat16(c0[0] + v0.x);
        preF[tb0 + 1] = __float2bfloat16(c0[1] + v0.y);
        preF[tb0 + 2] = __float2bfloat16(c0[2] + v0.z);
        preF[tb0 + 3] = __float2bfloat16(c0[3] + v0.w);
        preF[tb1 + 0] = __float2bfloat16(c1[0] + v1.x);
        preF[tb1 + 1] = __float2bfloat16(c1[1] + v1.y);
        preF[tb1 + 2] = __float2bfloat16(c1[2] + v1.z);
        preF[tb1 + 3] = __float2bfloat16(c1[3] + v1.w);
    }
}

// ---------------- persistent recurrence kernel (transposed gates) ----------------
// 512 blocks x 1 wave (cooperative). Wave (bt,jt): batch rows bt*16..+15, gate cols
// jt*16..+15 of each of the 5 gate blocks. Gt = W^T.h^T via MFMA(A=W-frag, B=h-frag);
// lane holds batch row (lane&15), 4 consecutive gate cols -> 8B contiguous h/S stores.
// Coherence: ALL cross-wave traffic (barrier counter + h exchange) uses SYSTEM-scope
// RELAXED atomics -> sc0 sc1 set ON THE INSTRUCTION (bypass L1+L2, hit device coherent
// point), with NO buffer_inv/buffer_wbl2 fences -> W stays hot in LDS, preF stays
// cached. s_waitcnt vmcnt(0) before arrival makes h durable before the counter
// releases readers. Poll is BOUNDED (deadlock -> fast wrong answer, never a hang).
__global__ __launch_bounds__(64, 1) void lstm_persist(const short8* __restrict__ WHsw,
                                                      const __hip_bfloat16* __restrict__ preF,
                                                      __hip_bfloat16* __restrict__ h0,
                                                      __hip_bfloat16* __restrict__ h1,
                                                      __hip_bfloat16* __restrict__ S,
                                                      int* __restrict__ bars) {
    __shared__ short8 ldsB[4096];   // 64 KB: 4 gate W-tiles x 16KB, fragment order
    int wid = blockIdx.x;           // 0..511
    int bt = wid >> 5, jt = wid & 31;
    int lane = threadIdx.x;
    int li = lane & 15, q = lane >> 4;

    // stage W tiles for gates 0..3 -> LDS (linear copy of frag-order tiles)
#pragma unroll
    for (int g = 0; g < 4; ++g) {
        const char* src = (const char*)(WHsw + (size_t)(g * 32 + jt) * 1024) + lane * 16;
        char* dst = (char*)ldsB + g * 16384;
#pragma unroll
        for (int i = 0; i < 16; ++i) gload_lds16(src + i * 1024, dst + i * 1024);
    }
    // sentinel-gate W tile -> registers
    short8 b4[16];
    const short8* B4 = WHsw + (size_t)(128 + jt) * 1024 + lane;
#pragma unroll
    for (int kt = 0; kt < 16; ++kt) b4[kt] = B4[kt * 64];
    __syncthreads();   // drains vmcnt -> gload_lds data usable

    int* cnt = bars + bt * 64;            // one cacheline per group
    f32x4 cacc = {0.f, 0.f, 0.f, 0.f};    // c[row bt*16+li][cols jt*16+q*4..+3]

    int hin  = (bt * 16 + li) * 1024 + q * 16;              // h frag load base (bytes)
    int hout = (bt * 16 + li) * 1024 + (jt * 16 + q * 4) * 2; // h/S store base (bytes)

    // preF stream: ull index = t*163840 + bt*10240 + g*2048 + jt*64 + lane
    const ull* ppw = (const ull*)preF + ((size_t)bt * 160 + jt) * 64 + lane;

    ull pp[5];
#pragma unroll
    for (int g = 0; g < 5; ++g) pp[g] = ppw[g * 2048];

    for (int t = 0; t < TT; ++t) {
        const __hip_bfloat16* hc = (t & 1) ? h1 : h0;
        __hip_bfloat16*       hn = (t & 1) ? h0 : h1;

        // prefetch next step's pre fragments (plain cached; overlaps the poll)
        ull ppn[5];
        if (t + 1 < TT) {
            const ull* pn = ppw + (size_t)(t + 1) * 163840;
#pragma unroll
            for (int g = 0; g < 5; ++g) ppn[g] = pn[g * 2048];
        }

        // wait: all 32 waves of this bt-group finished step t-1 (monotonic counter)
        if (t > 0) {
            int tgt = 32 * t;
            int v = __hip_atomic_load(cnt, __ATOMIC_RELAXED, __HIP_MEMORY_SCOPE_SYSTEM);
            for (int it = 0; v < tgt && it < 4000; ++it) {
                __builtin_amdgcn_s_sleep(8);
                v = __hip_atomic_load(cnt, __ATOMIC_RELAXED, __HIP_MEMORY_SCOPE_SYSTEM);
            }
        }

        // h fragments: 32 x 8B system-scope loads (coherent point; pipelined)
        const ull* hp = (const ull*)((const char*)hc + hin);
        ull hf[32];
#pragma unroll
        for (int kt = 0; kt < 16; ++kt) {
            hf[2 * kt]     = __hip_atomic_load(hp + kt * 8,     __ATOMIC_RELAXED, __HIP_MEMORY_SCOPE_SYSTEM);
            hf[2 * kt + 1] = __hip_atomic_load(hp + kt * 8 + 1, __ATOMIC_RELAXED, __HIP_MEMORY_SCOPE_SYSTEM);
        }

        f32x4 g0 = {0.f, 0.f, 0.f, 0.f}, g1 = g0, g2 = g0, g3 = g0, g4 = g0;
#pragma unroll
        for (int kt = 0; kt < 16; ++kt) {
            U16 hv; hv.u[0] = hf[2 * kt]; hv.u[1] = hf[2 * kt + 1];
            short8 bv = hv.s8;
            g0 = MFMA16(ldsB[       kt * 64 + lane], bv, g0);
            g1 = MFMA16(ldsB[1024 + kt * 64 + lane], bv, g1);
            g2 = MFMA16(ldsB[2048 + kt * 64 + lane], bv, g2);
            g3 = MFMA16(ldsB[3072 + kt * 64 + lane], bv, g3);
            g4 = MFMA16(b4[kt], bv, g4);
        }

        ull hvout = 0ull, svout = 0ull;
#pragma unroll
        for (int r = 0; r < 4; ++r) {
            float ig = sigf(g0[r] + bf2f((short)(pp[0] >> (16 * r))));
            float fg = sigf(g1[r] + bf2f((short)(pp[1] >> (16 * r))));
            float gg = tanhf(g2[r] + bf2f((short)(pp[2] >> (16 * r))));
            float og = sigf(g3[r] + bf2f((short)(pp[3] >> (16 * r))));
            float gp = sigf(g4[r] + bf2f((short)(pp[4] >> (16 * r))));
            float cn = fg * cacc[r] + ig * gg;
            float tc = tanhf(cn);
            cacc[r] = cn;
            hvout |= ((ull)(unsigned short)f2bfs(og * tc)) << (16 * r);
            svout |= ((ull)(unsigned short)f2bfs(gp * tc)) << (16 * r);
        }

        __hip_atomic_store((ull*)((char*)hn + hout), hvout,
                           __ATOMIC_RELAXED, __HIP_MEMORY_SCOPE_SYSTEM);
        *(ull*)((char*)S + (size_t)t * 262144 + hout) = svout;
        asm volatile("s_waitcnt vmcnt(0)" ::: "memory");
        if (lane == 0)
            __hip_atomic_fetch_add(cnt, 1, __ATOMIC_RELAXED, __HIP_MEMORY_SCOPE_SYSTEM);

#pragma unroll
        for (int g = 0; g < 5; ++g) pp[g] = ppn[g];
    }
}

// ---------------- fused output GEMM + sum-exp ----------------

__global__ __launch_bounds__(256) void lse_gemm(const short8* __restrict__ S8,
                                                const short8* __restrict__ Bsw,
                                                const float* __restrict__ ob,
                                                float* __restrict__ sumexp) {
    __shared__ short8 lds[2][1024];
    int w = threadIdx.x >> 6, lane = threadIdx.x & 63, li = lane & 15, q = lane >> 4;
    int r0 = blockIdx.x * 128 + w * 32;
    short8 a0[16], a1[16];
    const short8* Sp0 = S8 + (size_t)(r0 + li) * 64 + q;
    const short8* Sp1 = S8 + (size_t)(r0 + 16 + li) * 64 + q;
#pragma unroll
    for (int kt = 0; kt < 16; kt++) { a0[kt] = Sp0[kt * 4]; a1[kt] = Sp1[kt * 4]; }

    float s0[4] = {0.f,0.f,0.f,0.f}, s1[4] = {0.f,0.f,0.f,0.f};
    int t0 = blockIdx.y * 40;
    int t1 = t0 + 40 < NTILES ? t0 + 40 : NTILES;   // last chunk = 26

    stage_tile(Bsw + (size_t)t0 * 1024, lds[0], w, lane);
    int ib = 0;
    for (int ct = t0; ct < t1; ++ct, ib ^= 1) {
        __syncthreads();
        if (ct + 1 < t1) stage_tile(Bsw + (size_t)(ct + 1) * 1024, lds[ib ^ 1], w, lane);
        const short8* B = lds[ib];
        f32x4 c0 = {0.f,0.f,0.f,0.f}, c1 = {0.f,0.f,0.f,0.f};
#pragma unroll
        for (int kt = 0; kt < 16; kt++) {
            short8 bv = B[kt * 64 + lane];
            c0 = MFMA16(a0[kt], bv, c0);
            c1 = MFMA16(a1[kt], bv, c1);
        }
        int col = ct * 16 + li;
        if (col < NV) {
            float obv = ob[col];
#pragma unroll
            for (int r = 0; r < 4; r++) {
                s0[r] += __expf(c0[r] + obv);
                s1[r] += __expf(c1[r] + obv);
            }
        }
    }
#pragma unroll
    for (int off = 1; off < 16; off <<= 1) {
#pragma unroll
        for (int r = 0; r < 4; r++) { s0[r] += __shfl_xor(s0[r], off); s1[r] += __shfl_xor(s1[r], off); }
    }
    if (li == 0) {
#pragma unroll
        for (int r = 0; r < 4; r++) {
            atomicAdd(&sumexp[r0 + q * 4 + r], s0[r]);
            atomicAdd(&sumexp[r0 + 16 + q * 4 + r], s1[r]);
        }
    }
}

// out[row] = mask * (dot(S[row], out_W[:,tgt]) + ob[tgt] - log(sumexp[row]))
__global__ __launch_bounds__(256) void finalize_k(const __hip_bfloat16* __restrict__ S,
                                                  const __hip_bfloat16* __restrict__ Wt,
                                                  const float* __restrict__ ob,
                                                  const int* __restrict__ seqz,
                                                  const float* __restrict__ sumexp,
                                                  float* __restrict__ out) {
    int w = threadIdx.x >> 6, lane = threadIdx.x & 63;
    int row = blockIdx.x * 4 + w;        // 16384 rows, row = t*256 + b
    int t = row >> 8, b = row & 255;
    int tgt = seqz[b * TT + t];
    short8 sv = ((const short8*)(S + (size_t)row * 512))[lane];
    short8 wv = ((const short8*)(Wt + (size_t)tgt * 512))[lane];
    float d = 0.f;
#pragma unroll
    for (int i = 0; i < 8; i++) d += bf2f(sv[i]) * bf2f(wv[i]);
#pragma unroll
    for (int off = 1; off < 64; off <<= 1) d += __shfl_xor(d, off);
    if (lane == 0) {
        bool mk = (t == 0) || (seqz[b * TT + t - 1] != 0);
        out[row] = mk ? (d + ob[tgt] - logf(sumexp[row])) : 0.f;
    }
}

// ---------------- host ----------------

extern "C" void kernel_launch(void* const* d_in, const int* in_sizes, int n_in,
                              void* d_out, int out_size, void* d_ws, size_t ws_size,
                              hipStream_t stream) {
    const float* vis     = (const float*)d_in[0];
    const int*   seqz    = (const int*)d_in[1];
    const float* emb     = (const float*)d_in[2];
    const float* W_ih    = (const float*)d_in[3];
    const float* W_hh    = (const float*)d_in[4];
    const float* b_lstm  = (const float*)d_in[5];
    const float* vis2g_W = (const float*)d_in[6];
    const float* vis2g_b = (const float*)d_in[7];
    const float* w2g_W   = (const float*)d_in[8];
    const float* h2g_W   = (const float*)d_in[9];
    const float* out_W   = (const float*)d_in[10];
    const float* out_b   = (const float*)d_in[11];
    float* out = (float*)d_out;

    char* p = (char*)d_ws;
    auto carve = [&](size_t bytes) {
        void* r = (void*)p;
        p += (bytes + 255) & ~(size_t)255;
        return r;
    };
    __hip_bfloat16* WcatW = (__hip_bfloat16*)carve((size_t)NC * 512 * 2);       // [2560][512]
    __hip_bfloat16* WcatH = (__hip_bfloat16*)carve((size_t)NC * 512 * 2);       // [2560][512]
    __hip_bfloat16* visWt = (__hip_bfloat16*)carve((size_t)NC * 1024 * 2);      // [2560][1024]
    __hip_bfloat16* outWt = (__hip_bfloat16*)carve((size_t)NVP * 512 * 2);      // [10016][512]
    short8*         outSw = (short8*)carve((size_t)NTILES * 16384);             // frag order
    short8*         preBsw= (short8*)carve((size_t)160 * 16384);                // frag order
    short8*         WHsw  = (short8*)carve((size_t)160 * 16384);                // frag order
    __hip_bfloat16* visB  = (__hip_bfloat16*)carve((size_t)256 * 1024 * 2);
    float*          visC  = (float*)carve((size_t)256 * NC * 4);
    __hip_bfloat16* preF  = (__hip_bfloat16*)carve((size_t)TT * 256 * NC * 2);  // 84 MB, frag order
    float*          cbuf  = (float*)carve((size_t)256 * 512 * 4);               // unused by persist (c in regs)
    __hip_bfloat16* hb0   = (__hip_bfloat16*)carve((size_t)256 * 512 * 2);
    __hip_bfloat16* hb1   = (__hip_bfloat16*)carve((size_t)256 * 512 * 2);
    __hip_bfloat16* S     = (__hip_bfloat16*)carve((size_t)TT * 256 * 512 * 2);
    float*          sume  = (float*)carve((size_t)TT * 256 * 4);
    int*            bars  = (int*)carve((size_t)16 * 64 * 4);                   // 16 group counters

    dim3 tb(32, 8);
    // WcatW: word -> [gates | w2g];  WcatH: h -> [gates | h2g]   (both [2560][512] = [N][K])
    transpose_cvt<<<dim3(64, 16), tb, 0, stream>>>(W_ih + 1024 * 2048, 512, 2048, 2048, WcatW, 512, 2048);
    transpose_cvt<<<dim3(16, 16), tb, 0, stream>>>(w2g_W, 512, 512, 512, WcatW + 2048 * 512, 512, 512);
    transpose_cvt<<<dim3(64, 16), tb, 0, stream>>>(W_hh, 512, 2048, 2048, WcatH, 512, 2048);
    transpose_cvt<<<dim3(16, 16), tb, 0, stream>>>(h2g_W, 512, 512, 512, WcatH + 2048 * 512, 512, 512);
    // visWt: vis -> [gates | vis2g]  [2560][1024]
    transpose_cvt<<<dim3(64, 32), tb, 0, stream>>>(W_ih, 1024, 2048, 2048, visWt, 1024, 2048);
    transpose_cvt<<<dim3(16, 32), tb, 0, stream>>>(vis2g_W, 1024, 512, 512, visWt + 2048 * 1024, 1024, 512);
    // out_W transposed, zero-padded to 10016 rows
    transpose_cvt<<<dim3(313, 16), tb, 0, stream>>>(out_W, 512, NV, NV, outWt, 512, NVP);
    // fragment-order swizzles
    swizzle_frag<<<2504, 256, 0, stream>>>((const short8*)outWt, outSw, NTILES);
    swizzle_frag<<<640, 256, 0, stream>>>((const short8*)WcatW, preBsw, 160);
    swizzle_frag<<<640, 256, 0, stream>>>((const short8*)WcatH, WHsw, 160);

    zero_state<<<512, 256, 0, stream>>>(cbuf, hb0);
    cvt_vis<<<1024, 256, 0, stream>>>(vis, visB);
    gemm_vis<<<640, 256, 0, stream>>>(visB, visWt, b_lstm, vis2g_b, visC);
    pre_gemm<<<dim3(128, 8), 256, 0, stream>>>(seqz, emb, preBsw, visC, preF);

    hipMemsetAsync(sume, 0, (size_t)TT * 256 * 4, stream);
    hipMemsetAsync(bars, 0, (size_t)16 * 64 * 4, stream);

    // all 64 recurrence steps in one cooperative persistent kernel
    {
        const short8* WHsw_c = (const short8*)WHsw;
        const __hip_bfloat16* preF_c = (const __hip_bfloat16*)preF;
        __hip_bfloat16* h0a = hb0;
        __hip_bfloat16* h1a = hb1;
        __hip_bfloat16* Sa = S;
        int* barsa = bars;
        void* kargs[6] = { &WHsw_c, &preF_c, &h0a, &h1a, &Sa, &barsa };
        hipLaunchCooperativeKernel((void*)lstm_persist, dim3(512), dim3(64), kargs, 0, stream);
    }

    lse_gemm<<<dim3(128, 16), 256, 0, stream>>>((const short8*)S, outSw, out_b, sume);
    finalize_k<<<4096, 256, 0, stream>>>(S, outWt, out_b, seqz, sume, out);
}